// Round 4
// baseline (291.843 us; speedup 1.0000x reference)
//
#include <hip/hip_runtime.h>

#define HD 4
#define D 64
#define NHD 256   // HD*D
#define N_IN 256

typedef __attribute__((ext_vector_type(8))) __bf16 bf16x8;
typedef __attribute__((ext_vector_type(4))) __bf16 bf16x4;
typedef __attribute__((ext_vector_type(4))) float f32x4;

constexpr int AROW = 40;   // padded LDS row stride in bf16 (80B = 16B-multiple; 2-way banks = free)

// ---- K1: fused W transpose->bf16 (blocks 0..255) + XCD-privatized in-degree (rest) ----
__global__ __launch_bounds__(256) void pre_kernel(const float* __restrict__ W,
                                                  __bf16* __restrict__ Wt,
                                                  const int* __restrict__ ei,
                                                  int* __restrict__ deg8, int Nn, int E) {
  const int b = blockIdx.x;
  if (b < N_IN) {
    const int k = b, n = threadIdx.x;
    Wt[n * N_IN + k] = (__bf16)W[k * NHD + n];
  } else {
    const int e = (b - N_IN) * 256 + threadIdx.x;
    const int c = b & 7;   // plane = XCD under round-robin dispatch -> XCD-local atomics
    if (e < E) atomicAdd(&deg8[c * Nn + ei[E + e]], 1);
  }
}

// ---- K2: fused scan pass 1 (blocks 0..NB-1) + MFMA GEMM (rest) ----
__global__ __launch_bounds__(256) void gemm_scan_kernel(
    const float* __restrict__ A, const __bf16* __restrict__ Wt,
    const float* __restrict__ a_src, const float* __restrict__ a_dst,
    __bf16* __restrict__ hp16, float* __restrict__ s_out, float* __restrict__ t_out,
    int M, const int* __restrict__ deg8, int* __restrict__ partial,
    int* __restrict__ blocksum, int NB, int MT) {
  __shared__ __bf16 As[128 * AROW];
  __shared__ __bf16 Bs[128 * AROW];
  __shared__ int ws4[4];
  const int tid = threadIdx.x;

  if ((int)blockIdx.x < NB) {
    // ---------------- scan1: per-1024-node chunk scan of total degrees ----------------
    const int lane = tid & 63, wv = tid >> 6;
    const int base = blockIdx.x * 1024 + tid * 4;
    int v[4];
#pragma unroll
    for (int j = 0; j < 4; ++j) {
      int n = base + j;
      int sum = 0;
      if (n < M) {
#pragma unroll
        for (int c = 0; c < 8; ++c) sum += deg8[c * M + n];
      }
      v[j] = sum;
    }
    int sum = v[0] + v[1] + v[2] + v[3];
    int incl = sum;
#pragma unroll
    for (int off = 1; off < 64; off <<= 1) {
      int y = __shfl_up(incl, off);
      if (lane >= off) incl += y;
    }
    if (lane == 63) ws4[wv] = incl;
    __syncthreads();
    int wbase = 0;
#pragma unroll
    for (int w = 0; w < 4; ++w)
      if (w < wv) wbase += ws4[w];
    int excl = wbase + incl - sum;
    if (base + 0 < M) partial[base + 0] = excl;
    if (base + 1 < M) partial[base + 1] = excl + v[0];
    if (base + 2 < M) partial[base + 2] = excl + v[0] + v[1];
    if (base + 3 < M) partial[base + 3] = excl + v[0] + v[1] + v[2];
    if (tid == 255) blocksum[blockIdx.x] = wbase + incl;
    return;
  }

  // ---------------- gemm: hp16 = bf16(h @ W), 128x128 tile, fused s/t ----------------
  const int g = blockIdx.x - NB;
  const int bx = g % MT, by = g / MT;
  const int lane = tid & 63, wv = tid >> 6;
  const int wr = wv >> 1, wc = wv & 1;
  const int c15 = lane & 15, quad = lane >> 4;
  const int m0 = bx * 128, n0 = by * 128;

  f32x4 acc[4][4];
#pragma unroll
  for (int i = 0; i < 4; ++i)
#pragma unroll
    for (int j = 0; j < 4; ++j) acc[i][j] = (f32x4){0.f, 0.f, 0.f, 0.f};

  const int am = tid >> 1, aks = (tid & 1) * 16;
  const int gr = m0 + am;
  const bool arow_ok = (gr < M);
  const float* Arow = &A[(size_t)gr * N_IN];
  const __bf16* Brow = &Wt[(size_t)(n0 + am) * N_IN];

  for (int kc = 0; kc < 8; ++kc) {
    const int k0 = kc * 32;
    float4 f0, f1, f2, f3;
    if (arow_ok) {
      f0 = *(const float4*)&Arow[k0 + aks + 0];
      f1 = *(const float4*)&Arow[k0 + aks + 4];
      f2 = *(const float4*)&Arow[k0 + aks + 8];
      f3 = *(const float4*)&Arow[k0 + aks + 12];
    } else {
      f0 = f1 = f2 = f3 = make_float4(0.f, 0.f, 0.f, 0.f);
    }
    bf16x8 b0 = *(const bf16x8*)&Brow[k0 + aks];
    bf16x8 b1 = *(const bf16x8*)&Brow[k0 + aks + 8];

    __syncthreads();
    bf16x8 a0, a1;
    a0[0] = (__bf16)f0.x; a0[1] = (__bf16)f0.y; a0[2] = (__bf16)f0.z; a0[3] = (__bf16)f0.w;
    a0[4] = (__bf16)f1.x; a0[5] = (__bf16)f1.y; a0[6] = (__bf16)f1.z; a0[7] = (__bf16)f1.w;
    a1[0] = (__bf16)f2.x; a1[1] = (__bf16)f2.y; a1[2] = (__bf16)f2.z; a1[3] = (__bf16)f2.w;
    a1[4] = (__bf16)f3.x; a1[5] = (__bf16)f3.y; a1[6] = (__bf16)f3.z; a1[7] = (__bf16)f3.w;
    *(bf16x8*)&As[am * AROW + aks + 0] = a0;
    *(bf16x8*)&As[am * AROW + aks + 8] = a1;
    *(bf16x8*)&Bs[am * AROW + aks + 0] = b0;
    *(bf16x8*)&Bs[am * AROW + aks + 8] = b1;
    __syncthreads();

    bf16x8 af[4], bf_[4];
#pragma unroll
    for (int i = 0; i < 4; ++i) {
      af[i]  = *(bf16x8*)&As[(wr * 64 + i * 16 + c15) * AROW + quad * 8];
      bf_[i] = *(bf16x8*)&Bs[(wc * 64 + i * 16 + c15) * AROW + quad * 8];
    }
#pragma unroll
    for (int mi = 0; mi < 4; ++mi)
#pragma unroll
      for (int ni = 0; ni < 4; ++ni)
        acc[mi][ni] = __builtin_amdgcn_mfma_f32_16x16x32_bf16(af[mi], bf_[ni], acc[mi][ni], 0, 0, 0);
  }

  const int head = by * 2 + wc;
  float av[4], ad[4];
#pragma unroll
  for (int ni = 0; ni < 4; ++ni) {
    av[ni] = a_src[head * D + ni * 16 + c15];
    ad[ni] = a_dst[head * D + ni * 16 + c15];
  }
  const int row0w = m0 + wr * 64;
#pragma unroll
  for (int mi = 0; mi < 4; ++mi) {
#pragma unroll
    for (int j = 0; j < 4; ++j) {
      float ps = acc[mi][0][j] * av[0] + acc[mi][1][j] * av[1] +
                 acc[mi][2][j] * av[2] + acc[mi][3][j] * av[3];
      float pt = acc[mi][0][j] * ad[0] + acc[mi][1][j] * ad[1] +
                 acc[mi][2][j] * ad[2] + acc[mi][3][j] * ad[3];
#pragma unroll
      for (int m = 1; m < 16; m <<= 1) {
        ps += __shfl_xor(ps, m);
        pt += __shfl_xor(pt, m);
      }
      const int row = row0w + mi * 16 + quad * 4 + j;
      if (c15 == 0 && row < M) {
        s_out[row * HD + head] = ps;
        t_out[row * HD + head] = pt;
      }
    }
#pragma unroll
    for (int ni = 0; ni < 4; ++ni) {
#pragma unroll
      for (int j = 0; j < 4; ++j) {
        const int row = row0w + mi * 16 + quad * 4 + j;
        const int col = n0 + wc * 64 + ni * 16 + c15;
        if (row < M) hp16[(size_t)row * NHD + col] = (__bf16)acc[mi][ni][j];
      }
    }
  }
}

// ---- K3: scan 2+3: block-offset scan + per-node row_ptr + per-(node,plane) cursors ----
__global__ __launch_bounds__(256) void scan23_kernel(const int* __restrict__ partial,
                                                     const int* __restrict__ blocksum,
                                                     const int* __restrict__ deg8,
                                                     int* __restrict__ row_ptr,
                                                     int* __restrict__ cursor8, int n, int NB) {
  __shared__ int s_off;
  const int tid = threadIdx.x;
  if (tid < 64) {
    int v = (tid < NB) ? blocksum[tid] : 0;
    int incl = v;
#pragma unroll
    for (int off = 1; off < 64; off <<= 1) {
      int y = __shfl_up(incl, off);
      if (tid >= off) incl += y;
    }
    int prev = __shfl_up(incl, 1);
    int excl = (tid == 0) ? 0 : prev;
    if (tid == (int)blockIdx.x) s_off = excl;
    if (blockIdx.x == 0 && tid == NB - 1) row_ptr[n] = incl;   // grand total
  }
  __syncthreads();
  const int off = s_off;
  const int base = blockIdx.x * 1024 + tid * 4;
#pragma unroll
  for (int j = 0; j < 4; ++j) {
    const int node = base + j;
    if (node < n) {
      int rp = partial[node] + off;
      row_ptr[node] = rp;
      int run = rp;
#pragma unroll
      for (int c = 0; c < 8; ++c) {
        cursor8[c * n + node] = run;
        run += deg8[c * n + node];
      }
    }
  }
}

// ---- K4: per-edge scatter into CSR, XCD-privatized cursors ----
__global__ void scatter_kernel(const int* __restrict__ ei, int* __restrict__ cursor8,
                               int* __restrict__ csr_src, int Nn, int E) {
  int e = blockIdx.x * blockDim.x + threadIdx.x;
  if (e >= E) return;
  const int c = blockIdx.x & 7;   // same plane choice as pre_kernel's degree pass
  int sn = ei[e], dn = ei[E + e];
  int pos = atomicAdd(&cursor8[c * Nn + dn], 1);
  csr_src[pos] = sn;
}

// ---- K5: per-dst aggregation: 1 wave/node, 4 dims/lane, 4 gathers in flight ----
//      node-range arg: launched as 4 quarter dispatches (timestamp instrumentation:
//      inter-quarter Start-End deltas = in-graph launch gap; quarters surface other
//      kernels >~17us in the top-5 counter rows)
__global__ __launch_bounds__(256) void aggregate_kernel(
    const int* __restrict__ row_ptr, const int* __restrict__ csr_src,
    const float* __restrict__ s, const float* __restrict__ t,
    const __bf16* __restrict__ hp16, float* __restrict__ out, int node0, int node_end) {
  const int wave = threadIdx.x >> 6;
  const int lane = threadIdx.x & 63;
  const int node = node0 + blockIdx.x * 4 + wave;
  if (node >= node_end) return;
  const int h = lane >> 4;
  const int d0 = lane * 4;
  const int beg = row_ptr[node], end = row_ptr[node + 1];
  const float tn = t[node * HD + h];
  float num0 = 0.f, num1 = 0.f, num2 = 0.f, num3 = 0.f, den = 0.f;
  int i = beg;
  for (; i + 4 <= end; i += 4) {
    int sn0 = csr_src[i], sn1 = csr_src[i + 1], sn2 = csr_src[i + 2], sn3 = csr_src[i + 3];
    bf16x4 v0 = *(const bf16x4*)&hp16[(size_t)sn0 * NHD + d0];
    bf16x4 v1 = *(const bf16x4*)&hp16[(size_t)sn1 * NHD + d0];
    bf16x4 v2 = *(const bf16x4*)&hp16[(size_t)sn2 * NHD + d0];
    bf16x4 v3 = *(const bf16x4*)&hp16[(size_t)sn3 * NHD + d0];
    float lg0 = s[sn0 * HD + h] + tn;
    float lg1 = s[sn1 * HD + h] + tn;
    float lg2 = s[sn2 * HD + h] + tn;
    float lg3 = s[sn3 * HD + h] + tn;
    lg0 = fmaxf(lg0, 0.2f * lg0);
    lg1 = fmaxf(lg1, 0.2f * lg1);
    lg2 = fmaxf(lg2, 0.2f * lg2);
    lg3 = fmaxf(lg3, 0.2f * lg3);
    float ex0 = __expf(lg0), ex1 = __expf(lg1), ex2 = __expf(lg2), ex3 = __expf(lg3);
    den += (ex0 + ex1) + (ex2 + ex3);
    num0 += ex0 * (float)v0[0] + ex1 * (float)v1[0] + ex2 * (float)v2[0] + ex3 * (float)v3[0];
    num1 += ex0 * (float)v0[1] + ex1 * (float)v1[1] + ex2 * (float)v2[1] + ex3 * (float)v3[1];
    num2 += ex0 * (float)v0[2] + ex1 * (float)v1[2] + ex2 * (float)v2[2] + ex3 * (float)v3[2];
    num3 += ex0 * (float)v0[3] + ex1 * (float)v1[3] + ex2 * (float)v2[3] + ex3 * (float)v3[3];
  }
  for (; i < end; ++i) {
    int sn0 = csr_src[i];
    bf16x4 v0 = *(const bf16x4*)&hp16[(size_t)sn0 * NHD + d0];
    float lg0 = s[sn0 * HD + h] + tn;
    lg0 = fmaxf(lg0, 0.2f * lg0);
    float ex0 = __expf(lg0);
    den += ex0;
    num0 += ex0 * (float)v0[0];
    num1 += ex0 * (float)v0[1];
    num2 += ex0 * (float)v0[2];
    num3 += ex0 * (float)v0[3];
  }
  const float inv = 1.0f / (den + 1e-16f);
  float4 o = make_float4(num0 * inv, num1 * inv, num2 * inv, num3 * inv);
  *(float4*)&out[(size_t)node * NHD + d0] = o;
}

extern "C" void kernel_launch(void* const* d_in, const int* in_sizes, int n_in,
                              void* d_out, int out_size, void* d_ws, size_t ws_size,
                              hipStream_t stream) {
  const float* h_ptr  = (const float*)d_in[0];
  const int*   ei     = (const int*)d_in[1];
  const float* W      = (const float*)d_in[2];
  const float* a_src  = (const float*)d_in[3];
  const float* a_dst  = (const float*)d_in[4];
  float* out = (float*)d_out;

  const int N = in_sizes[0] / N_IN;     // 50000
  const int E = in_sizes[1] / 2;        // 800000
  const int NB = (N + 1023) / 1024;     // 49 scan chunks
  const int MT = (N + 127) / 128;       // 391 gemm m-tiles

  auto align256 = [](size_t x) { return (x + 255) & ~size_t(255); };
  char* base = (char*)d_ws;
  size_t off = 0;
  __bf16* hp16 = (__bf16*)(base + off);  off += align256((size_t)N * NHD * 2);
  __bf16* Wt   = (__bf16*)(base + off);  off += align256((size_t)N_IN * NHD * 2);
  float* s       = (float*)(base + off); off += align256((size_t)N * HD * 4);
  float* t       = (float*)(base + off); off += align256((size_t)N * HD * 4);
  int*   deg8    = (int*)(base + off);   off += align256((size_t)N * 8 * 4);
  int*   cursor8 = (int*)(base + off);   off += align256((size_t)N * 8 * 4);
  int*   partial = (int*)(base + off);   off += align256((size_t)N * 4);
  int*   blocksum= (int*)(base + off);   off += align256((size_t)NB * 4);
  int*   row_ptr = (int*)(base + off);   off += align256((size_t)(N + 1) * 4);
  int*   csr_src = (int*)(base + off);   off += align256((size_t)E * 4);

  // 0. zero privatized degree planes
  hipMemsetAsync(deg8, 0, (size_t)N * 8 * 4, stream);
  // 1. fused W-transpose + privatized degree
  pre_kernel<<<N_IN + (E + 255) / 256, 256, 0, stream>>>(W, Wt, ei, deg8, N, E);
  // 2. fused scan1 + MFMA GEMM (single-B bf16)
  gemm_scan_kernel<<<NB + MT * 2, 256, 0, stream>>>(h_ptr, Wt, a_src, a_dst,
                                                    hp16, s, t, N, deg8, partial,
                                                    blocksum, NB, MT);
  // 3. scan2+3 -> row_ptr + privatized cursors
  scan23_kernel<<<NB, 256, 0, stream>>>(partial, blocksum, deg8, row_ptr, cursor8, N, NB);
  // 4. per-edge scatter (privatized cursors)
  scatter_kernel<<<(E + 255) / 256, 256, 0, stream>>>(ei, cursor8, csr_src, N, E);
  // 5. per-dst aggregation, split into 4 quarter-dispatches for per-kernel visibility
  {
    const int q = (N + 3) / 4;                 // nodes per quarter (rounded)
    const int qa = (q + 3) & ~3;               // multiple of 4 (waves/block)
    for (int k = 0; k < 4; ++k) {
      const int n0 = k * qa;
      const int n1 = (k == 3) ? N : ((k + 1) * qa < N ? (k + 1) * qa : N);
      if (n1 > n0)
        aggregate_kernel<<<(n1 - n0 + 3) / 4, 256, 0, stream>>>(row_ptr, csr_src, s, t,
                                                                hp16, out, n0, n1);
    }
  }
}

// Round 5
// 282.915 us; speedup vs baseline: 1.0316x; 1.0316x over previous
//
#include <hip/hip_runtime.h>

#define HD 4
#define D 64
#define NHD 256   // HD*D
#define N_IN 256
#define NPB 128   // nodes per permute block

typedef __attribute__((ext_vector_type(8))) __bf16 bf16x8;
typedef __attribute__((ext_vector_type(4))) __bf16 bf16x4;
typedef __attribute__((ext_vector_type(4))) float f32x4;

constexpr int AROW = 40;   // padded LDS row stride in bf16 (80B = 16B-multiple; 2-way banks = free)

// ---- K1: fused W transpose->bf16 (blocks 0..255) + XCD-privatized in-degree (rest) ----
__global__ __launch_bounds__(256) void pre_kernel(const float* __restrict__ W,
                                                  __bf16* __restrict__ Wt,
                                                  const int* __restrict__ ei,
                                                  int* __restrict__ deg8, int Nn, int E) {
  const int b = blockIdx.x;
  if (b < N_IN) {
    const int k = b, n = threadIdx.x;
    Wt[n * N_IN + k] = (__bf16)W[k * NHD + n];
  } else {
    const int e = (b - N_IN) * 256 + threadIdx.x;
    const int c = b & 7;   // plane = XCD under round-robin dispatch -> XCD-local atomics
    if (e < E) atomicAdd(&deg8[c * Nn + ei[E + e]], 1);
  }
}

// ---- K2: fused scan pass 1 (blocks 0..NB-1; PER-PLANE chunk scans) + MFMA GEMM (rest) ----
__global__ __launch_bounds__(256) void gemm_scan_kernel(
    const float* __restrict__ A, const __bf16* __restrict__ Wt,
    const float* __restrict__ a_src, const float* __restrict__ a_dst,
    __bf16* __restrict__ hp16, float* __restrict__ s_out, float* __restrict__ t_out,
    int M, const int* __restrict__ deg8, int* __restrict__ partial8,
    int* __restrict__ blocksum8, int NB, int MT) {
  __shared__ __bf16 As[128 * AROW];
  __shared__ __bf16 Bs[128 * AROW];
  __shared__ int ws4[4];
  const int tid = threadIdx.x;

  if ((int)blockIdx.x < NB) {
    // scan1: per-1024-node chunk, per-plane exclusive prefix of deg8 + chunk plane sums
    const int lane = tid & 63, wv = tid >> 6;
    const int base = blockIdx.x * 1024 + tid * 4;
#pragma unroll 1
    for (int c = 0; c < 8; ++c) {
      int v0 = 0, v1 = 0, v2 = 0, v3 = 0;
      if (base + 3 < M) {
        int4 q = *(const int4*)&deg8[c * M + base];
        v0 = q.x; v1 = q.y; v2 = q.z; v3 = q.w;
      } else {
        if (base + 0 < M) v0 = deg8[c * M + base + 0];
        if (base + 1 < M) v1 = deg8[c * M + base + 1];
        if (base + 2 < M) v2 = deg8[c * M + base + 2];
        if (base + 3 < M) v3 = deg8[c * M + base + 3];
      }
      const int sum = v0 + v1 + v2 + v3;
      int incl = sum;
#pragma unroll
      for (int off = 1; off < 64; off <<= 1) {
        int y = __shfl_up(incl, off);
        if (lane >= off) incl += y;
      }
      if (lane == 63) ws4[wv] = incl;
      __syncthreads();
      int wbase = 0;
#pragma unroll
      for (int w = 0; w < 4; ++w)
        if (w < wv) wbase += ws4[w];
      __syncthreads();   // ws4 reused next plane
      const int excl = wbase + incl - sum;
      if (base + 0 < M) partial8[c * M + base + 0] = excl;
      if (base + 1 < M) partial8[c * M + base + 1] = excl + v0;
      if (base + 2 < M) partial8[c * M + base + 2] = excl + v0 + v1;
      if (base + 3 < M) partial8[c * M + base + 3] = excl + v0 + v1 + v2;
      if (tid == 255) blocksum8[c * NB + blockIdx.x] = wbase + incl;
    }
    return;
  }

  // ---------------- gemm: hp16 = bf16(h @ W), 128x128 tile, fused s/t ----------------
  const int g = blockIdx.x - NB;
  const int bx = g % MT, by = g / MT;
  const int lane = tid & 63, wv = tid >> 6;
  const int wr = wv >> 1, wc = wv & 1;
  const int c15 = lane & 15, quad = lane >> 4;
  const int m0 = bx * 128, n0 = by * 128;

  f32x4 acc[4][4];
#pragma unroll
  for (int i = 0; i < 4; ++i)
#pragma unroll
    for (int j = 0; j < 4; ++j) acc[i][j] = (f32x4){0.f, 0.f, 0.f, 0.f};

  const int am = tid >> 1, aks = (tid & 1) * 16;
  const int gr = m0 + am;
  const bool arow_ok = (gr < M);
  const float* Arow = &A[(size_t)gr * N_IN];
  const __bf16* Brow = &Wt[(size_t)(n0 + am) * N_IN];

  for (int kc = 0; kc < 8; ++kc) {
    const int k0 = kc * 32;
    float4 f0, f1, f2, f3;
    if (arow_ok) {
      f0 = *(const float4*)&Arow[k0 + aks + 0];
      f1 = *(const float4*)&Arow[k0 + aks + 4];
      f2 = *(const float4*)&Arow[k0 + aks + 8];
      f3 = *(const float4*)&Arow[k0 + aks + 12];
    } else {
      f0 = f1 = f2 = f3 = make_float4(0.f, 0.f, 0.f, 0.f);
    }
    bf16x8 b0 = *(const bf16x8*)&Brow[k0 + aks];
    bf16x8 b1 = *(const bf16x8*)&Brow[k0 + aks + 8];

    __syncthreads();
    bf16x8 a0, a1;
    a0[0] = (__bf16)f0.x; a0[1] = (__bf16)f0.y; a0[2] = (__bf16)f0.z; a0[3] = (__bf16)f0.w;
    a0[4] = (__bf16)f1.x; a0[5] = (__bf16)f1.y; a0[6] = (__bf16)f1.z; a0[7] = (__bf16)f1.w;
    a1[0] = (__bf16)f2.x; a1[1] = (__bf16)f2.y; a1[2] = (__bf16)f2.z; a1[3] = (__bf16)f2.w;
    a1[4] = (__bf16)f3.x; a1[5] = (__bf16)f3.y; a1[6] = (__bf16)f3.z; a1[7] = (__bf16)f3.w;
    *(bf16x8*)&As[am * AROW + aks + 0] = a0;
    *(bf16x8*)&As[am * AROW + aks + 8] = a1;
    *(bf16x8*)&Bs[am * AROW + aks + 0] = b0;
    *(bf16x8*)&Bs[am * AROW + aks + 8] = b1;
    __syncthreads();

    bf16x8 af[4], bf_[4];
#pragma unroll
    for (int i = 0; i < 4; ++i) {
      af[i]  = *(bf16x8*)&As[(wr * 64 + i * 16 + c15) * AROW + quad * 8];
      bf_[i] = *(bf16x8*)&Bs[(wc * 64 + i * 16 + c15) * AROW + quad * 8];
    }
#pragma unroll
    for (int mi = 0; mi < 4; ++mi)
#pragma unroll
      for (int ni = 0; ni < 4; ++ni)
        acc[mi][ni] = __builtin_amdgcn_mfma_f32_16x16x32_bf16(af[mi], bf_[ni], acc[mi][ni], 0, 0, 0);
  }

  const int head = by * 2 + wc;
  float av[4], ad[4];
#pragma unroll
  for (int ni = 0; ni < 4; ++ni) {
    av[ni] = a_src[head * D + ni * 16 + c15];
    ad[ni] = a_dst[head * D + ni * 16 + c15];
  }
  const int row0w = m0 + wr * 64;
#pragma unroll
  for (int mi = 0; mi < 4; ++mi) {
#pragma unroll
    for (int j = 0; j < 4; ++j) {
      float ps = acc[mi][0][j] * av[0] + acc[mi][1][j] * av[1] +
                 acc[mi][2][j] * av[2] + acc[mi][3][j] * av[3];
      float pt = acc[mi][0][j] * ad[0] + acc[mi][1][j] * ad[1] +
                 acc[mi][2][j] * ad[2] + acc[mi][3][j] * ad[3];
#pragma unroll
      for (int m = 1; m < 16; m <<= 1) {
        ps += __shfl_xor(ps, m);
        pt += __shfl_xor(pt, m);
      }
      const int row = row0w + mi * 16 + quad * 4 + j;
      if (c15 == 0 && row < M) {
        s_out[row * HD + head] = ps;
        t_out[row * HD + head] = pt;
      }
    }
#pragma unroll
    for (int ni = 0; ni < 4; ++ni) {
#pragma unroll
      for (int j = 0; j < 4; ++j) {
        const int row = row0w + mi * 16 + quad * 4 + j;
        const int col = n0 + wc * 64 + ni * 16 + c15;
        if (row < M) hp16[(size_t)row * NHD + col] = (__bf16)acc[mi][ni][j];
      }
    }
  }
}

// ---- K3: scan 2+3: per-plane chunk-offset scan + plane bases; emit row_ptr (node-major),
//      pcur0 (plane-major starts, read-only) and cursor8 (mutable copy for scatter) ----
__global__ __launch_bounds__(256) void scan23_kernel(
    const int* __restrict__ partial8, const int* __restrict__ blocksum8,
    int* __restrict__ row_ptr, int* __restrict__ pcur0, int* __restrict__ cursor8,
    int n, int NB) {
  __shared__ int s_choff[8], s_B[8], s_T[8];
  const int tid = threadIdx.x;
  if (tid < 64) {
    int runB = 0;
#pragma unroll 1
    for (int c = 0; c < 8; ++c) {
      int v = (tid < NB) ? blocksum8[c * NB + tid] : 0;
      int incl = v;
#pragma unroll
      for (int off = 1; off < 64; off <<= 1) {
        int y = __shfl_up(incl, off);
        if (tid >= off) incl += y;
      }
      const int excl = incl - v;
      const int choff = __shfl(excl, (int)blockIdx.x);   // this chunk's offset in plane c
      const int Tc = __shfl(incl, NB - 1);               // plane c total
      if (tid == 0) { s_choff[c] = choff; s_B[c] = runB; s_T[c] = Tc; }
      runB += Tc;
    }
    if (blockIdx.x == 0 && tid == 0) row_ptr[n] = runB;  // == E
  }
  __syncthreads();
  if (blockIdx.x == 0 && tid < 8)
    pcur0[tid * (n + 1) + n] = s_B[tid] + s_T[tid];      // plane region ends
  const int base = blockIdx.x * 1024 + tid * 4;
  int rp0 = 0, rp1 = 0, rp2 = 0, rp3 = 0;
  const bool full = (base + 3 < n);
#pragma unroll 1
  for (int c = 0; c < 8; ++c) {
    int p0 = 0, p1 = 0, p2 = 0, p3 = 0;
    if (full) {
      int4 q = *(const int4*)&partial8[c * n + base];
      p0 = q.x; p1 = q.y; p2 = q.z; p3 = q.w;
    } else {
      if (base + 0 < n) p0 = partial8[c * n + base + 0];
      if (base + 1 < n) p1 = partial8[c * n + base + 1];
      if (base + 2 < n) p2 = partial8[c * n + base + 2];
    }
    const int ch = s_choff[c], bB = s_B[c];
    if (base + 0 < n) { int P = ch + p0, pc = bB + P; pcur0[c*(n+1)+base+0] = pc; cursor8[c*n+base+0] = pc; rp0 += P; }
    if (base + 1 < n) { int P = ch + p1, pc = bB + P; pcur0[c*(n+1)+base+1] = pc; cursor8[c*n+base+1] = pc; rp1 += P; }
    if (base + 2 < n) { int P = ch + p2, pc = bB + P; pcur0[c*(n+1)+base+2] = pc; cursor8[c*n+base+2] = pc; rp2 += P; }
    if (base + 3 < n) { int P = ch + p3, pc = bB + P; pcur0[c*(n+1)+base+3] = pc; cursor8[c*n+base+3] = pc; rp3 += P; }
  }
  if (base + 0 < n) row_ptr[base + 0] = rp0;
  if (base + 1 < n) row_ptr[base + 1] = rp1;
  if (base + 2 < n) row_ptr[base + 2] = rp2;
  if (base + 3 < n) row_ptr[base + 3] = rp3;
}

// ---- K4: per-edge scatter into PLANE-MAJOR staging: plane c region written only by
//      XCD c's blocks -> every dirty line is single-L2-owned (kills the 16x HBM
//      write amplification the node-major scatter had) ----
__global__ void scatter_kernel(const int* __restrict__ ei, int* __restrict__ cursor8,
                               int* __restrict__ tmp_src, int Nn, int E) {
  int e = blockIdx.x * blockDim.x + threadIdx.x;
  if (e >= E) return;
  const int c = blockIdx.x & 7;   // same plane choice as pre_kernel's degree pass
  int sn = ei[e], dn = ei[E + e];
  int pos = atomicAdd(&cursor8[c * Nn + dn], 1);
  tmp_src[pos] = sn;
}

// ---- K4b: plane-major -> node-major CSR permute. Per 128-node block: 8 sequential
//      read streams, one contiguous ~8KB write window (single-block-owned lines). ----
__global__ __launch_bounds__(256) void permute_kernel(
    const int* __restrict__ pcur0, const int* __restrict__ row_ptr,
    const int* __restrict__ tmp_src, int* __restrict__ csr_src, int n) {
  __shared__ int spc[8][NPB + 1];   // plane-major starts for nodes n0..n1 (+end)
  __shared__ int sO[8][NPB];        // node-major offset of plane c within node's segment
  __shared__ int srp[NPB];          // row_ptr for node range
  const int tid = threadIdx.x;
  const int n0 = blockIdx.x * NPB;
  const int cnt = (n - n0 < NPB) ? (n - n0) : NPB;
  for (int idx = tid; idx < 8 * (NPB + 1); idx += 256) {
    const int c = idx / (NPB + 1), i = idx - c * (NPB + 1);
    int ni = n0 + i; if (ni > n) ni = n;      // clamp: entries past n1 repeat region end
    spc[c][i] = pcur0[c * (n + 1) + ni];
  }
  for (int i = tid; i < cnt; i += 256) srp[i] = row_ptr[n0 + i];
  __syncthreads();
  for (int i = tid; i < cnt; i += 256) {
    int run = 0;
#pragma unroll
    for (int c = 0; c < 8; ++c) { sO[c][i] = run; run += spc[c][i + 1] - spc[c][i]; }
  }
  __syncthreads();
  const int lane = tid & 63, wv = tid >> 6;
#pragma unroll 1
  for (int c = wv; c < 8; c += 4) {
    const int S = spc[c][0];
    const int L = spc[c][cnt] - S;
    for (int k = lane; k < L; k += 64) {
      const int q = S + k;
      const int val = tmp_src[q];                 // coalesced stream read
      int lo = 0, hi = cnt;                       // find node: spc[c][lo] <= q < spc[c][lo+1]
      while (hi - lo > 1) {
        const int mid = (lo + hi) >> 1;
        if (spc[c][mid] <= q) lo = mid; else hi = mid;
      }
      const int dest = srp[lo] + sO[c][lo] + (q - spc[c][lo]);
      csr_src[dest] = val;                        // write within block-local ~8KB window
    }
  }
}

// ---- K5: per-dst aggregation: 1 wave/node, 4 dims/lane, 4 gathers in flight ----
__global__ __launch_bounds__(256) void aggregate_kernel(
    const int* __restrict__ row_ptr, const int* __restrict__ csr_src,
    const float* __restrict__ s, const float* __restrict__ t,
    const __bf16* __restrict__ hp16, float* __restrict__ out, int N) {
  const int wave = threadIdx.x >> 6;
  const int lane = threadIdx.x & 63;
  const int node = blockIdx.x * 4 + wave;
  if (node >= N) return;
  const int h = lane >> 4;
  const int d0 = lane * 4;
  const int beg = row_ptr[node], end = row_ptr[node + 1];
  const float tn = t[node * HD + h];
  float num0 = 0.f, num1 = 0.f, num2 = 0.f, num3 = 0.f, den = 0.f;
  int i = beg;
  for (; i + 4 <= end; i += 4) {
    int sn0 = csr_src[i], sn1 = csr_src[i + 1], sn2 = csr_src[i + 2], sn3 = csr_src[i + 3];
    bf16x4 v0 = *(const bf16x4*)&hp16[(size_t)sn0 * NHD + d0];
    bf16x4 v1 = *(const bf16x4*)&hp16[(size_t)sn1 * NHD + d0];
    bf16x4 v2 = *(const bf16x4*)&hp16[(size_t)sn2 * NHD + d0];
    bf16x4 v3 = *(const bf16x4*)&hp16[(size_t)sn3 * NHD + d0];
    float lg0 = s[sn0 * HD + h] + tn;
    float lg1 = s[sn1 * HD + h] + tn;
    float lg2 = s[sn2 * HD + h] + tn;
    float lg3 = s[sn3 * HD + h] + tn;
    lg0 = fmaxf(lg0, 0.2f * lg0);
    lg1 = fmaxf(lg1, 0.2f * lg1);
    lg2 = fmaxf(lg2, 0.2f * lg2);
    lg3 = fmaxf(lg3, 0.2f * lg3);
    float ex0 = __expf(lg0), ex1 = __expf(lg1), ex2 = __expf(lg2), ex3 = __expf(lg3);
    den += (ex0 + ex1) + (ex2 + ex3);
    num0 += ex0 * (float)v0[0] + ex1 * (float)v1[0] + ex2 * (float)v2[0] + ex3 * (float)v3[0];
    num1 += ex0 * (float)v0[1] + ex1 * (float)v1[1] + ex2 * (float)v2[1] + ex3 * (float)v3[1];
    num2 += ex0 * (float)v0[2] + ex1 * (float)v1[2] + ex2 * (float)v2[2] + ex3 * (float)v3[2];
    num3 += ex0 * (float)v0[3] + ex1 * (float)v1[3] + ex2 * (float)v2[3] + ex3 * (float)v3[3];
  }
  for (; i < end; ++i) {
    int sn0 = csr_src[i];
    bf16x4 v0 = *(const bf16x4*)&hp16[(size_t)sn0 * NHD + d0];
    float lg0 = s[sn0 * HD + h] + tn;
    lg0 = fmaxf(lg0, 0.2f * lg0);
    float ex0 = __expf(lg0);
    den += ex0;
    num0 += ex0 * (float)v0[0];
    num1 += ex0 * (float)v0[1];
    num2 += ex0 * (float)v0[2];
    num3 += ex0 * (float)v0[3];
  }
  const float inv = 1.0f / (den + 1e-16f);
  float4 o = make_float4(num0 * inv, num1 * inv, num2 * inv, num3 * inv);
  *(float4*)&out[(size_t)node * NHD + d0] = o;
}

extern "C" void kernel_launch(void* const* d_in, const int* in_sizes, int n_in,
                              void* d_out, int out_size, void* d_ws, size_t ws_size,
                              hipStream_t stream) {
  const float* h_ptr  = (const float*)d_in[0];
  const int*   ei     = (const int*)d_in[1];
  const float* W      = (const float*)d_in[2];
  const float* a_src  = (const float*)d_in[3];
  const float* a_dst  = (const float*)d_in[4];
  float* out = (float*)d_out;

  const int N = in_sizes[0] / N_IN;     // 50000
  const int E = in_sizes[1] / 2;        // 800000
  const int NB = (N + 1023) / 1024;     // 49 scan chunks
  const int MT = (N + 127) / 128;       // 391 gemm m-tiles

  auto align256 = [](size_t x) { return (x + 255) & ~size_t(255); };
  char* base = (char*)d_ws;
  size_t off = 0;
  __bf16* hp16 = (__bf16*)(base + off);  off += align256((size_t)N * NHD * 2);
  __bf16* Wt   = (__bf16*)(base + off);  off += align256((size_t)N_IN * NHD * 2);
  float* s        = (float*)(base + off); off += align256((size_t)N * HD * 4);
  float* t        = (float*)(base + off); off += align256((size_t)N * HD * 4);
  int*   deg8     = (int*)(base + off);   off += align256((size_t)N * 8 * 4);
  int*   cursor8  = (int*)(base + off);   off += align256((size_t)N * 8 * 4);
  int*   partial8 = (int*)(base + off);   off += align256((size_t)N * 8 * 4);
  int*   blocksum8= (int*)(base + off);   off += align256((size_t)NB * 8 * 4);
  int*   row_ptr  = (int*)(base + off);   off += align256((size_t)(N + 1) * 4);
  int*   pcur0    = (int*)(base + off);   off += align256((size_t)(N + 1) * 8 * 4);
  int*   tmp_src  = (int*)(base + off);   off += align256((size_t)E * 4);
  int*   csr_src  = (int*)(base + off);   off += align256((size_t)E * 4);

  // 0. zero privatized degree planes
  hipMemsetAsync(deg8, 0, (size_t)N * 8 * 4, stream);
  // 1. fused W-transpose + privatized degree
  pre_kernel<<<N_IN + (E + 255) / 256, 256, 0, stream>>>(W, Wt, ei, deg8, N, E);
  // 2. fused per-plane scan1 + MFMA GEMM
  gemm_scan_kernel<<<NB + MT * 2, 256, 0, stream>>>(h_ptr, Wt, a_src, a_dst,
                                                    hp16, s, t, N, deg8, partial8,
                                                    blocksum8, NB, MT);
  // 3. scan2+3 -> row_ptr + plane-major pcur0/cursor8
  scan23_kernel<<<NB, 256, 0, stream>>>(partial8, blocksum8, row_ptr, pcur0, cursor8, N, NB);
  // 4. per-edge scatter into plane-major staging (XCD-local lines)
  scatter_kernel<<<(E + 255) / 256, 256, 0, stream>>>(ei, cursor8, tmp_src, N, E);
  // 4b. plane-major -> node-major CSR
  permute_kernel<<<(N + NPB - 1) / NPB, 256, 0, stream>>>(pcur0, row_ptr, tmp_src, csr_src, N);
  // 5. per-dst aggregation (single dispatch)
  aggregate_kernel<<<(N + 3) / 4, 256, 0, stream>>>(row_ptr, csr_src, s, t, hp16, out, N);
}